// Round 10
// baseline (287.602 us; speedup 1.0000x reference)
//
#include <hip/hip_runtime.h>

// Per-pixel attention over 32 "boxes" (all fp32):
//   q,k,v: [32 box][4 batch][64 ch][6400 pix]
//   scores[i,j] = <q[i,:,p], k[j,:,p]> / 8 ; w = softmax_j ; out[i,c,p] = sum_j w[i,j] v[j,c,p]
//
// R10 vs R9: R9 was stall-bound with NOTHING saturated (VALU 35%, HBM 26%, LDS ~10%,
// Occ 19%) at the VGPR-forced ceiling of 4 waves/SIMD (s[2][32]=64 regs + prefetch =
// 124 VGPR). This round buys occupancy: each thread now owns HALF the boxes
// (s[2][16] = 32 regs, j-half split across thread pairs) -> ~80 live regs ->
// launch_bounds(512,3) targets cap 256/3 = 85 (empirical law, 3 data points) ->
// 6 waves/SIMD. Softmax/PV combine across the pair = one __shfl_xor(...,16) each
// (in-wave: lane = pp(4b) | jg(1b) | ig(4b... low 6 bits cover pp+jg)). PV: partners
// sum partials, then each writes 2 of 4 channels (pp in low lane bits keeps 64B write
// segments). LDS b128 reads: 32 unique addrs x 16B = 512B/wave = 4-cyc LDS minimum.
// Keeps: double-buffered LDS + sched_barrier-fenced SYNC (R7 race fix), 2-deep K and
// V prefetch, Q register double-buffer, XCD swizzle, PIX=16, CC=4.

#define NBOX    32
#define NBATCH  4
#define CH      64
#define HW      6400
#define PIX     16
#define CC      4
#define NCHUNK  (CH / CC)          // 16
#define NT      512
#define LPJ     36                 // LDS row stride in floats (32 j + 4 pad)
#define NTILES  (HW / PIX)         // 400
#define NUNITS  (NBATCH * NTILES)  // 1600
#define CSTRIDE ((size_t)CC * HW)  // elements per chunk step

#define SYNC() do { __builtin_amdgcn_sched_barrier(0); __syncthreads(); \
                    __builtin_amdgcn_sched_barrier(0); } while (0)

__global__ __launch_bounds__(NT, 3)
void box_attn_kernel(const float* __restrict__ q,
                     const float* __restrict__ k,
                     const float* __restrict__ v,
                     float* __restrict__ out) {
    __shared__ float lds[2][CC * PIX * LPJ];   // 2 x 9.2 KiB

    const int t   = threadIdx.x;
    const int bid = blockIdx.x;
    const int unit = (bid & 7) * (NUNITS / 8) + (bid >> 3);  // XCD swizzle (1600%8==0)
    const int b    = unit / NTILES;
    const int p0   = (unit % NTILES) * PIX;

    // compute mapping: lane = pp(4) | jg(1) | ig(4)
    const int pp = t & 15;          // pixel
    const int jg = (t >> 4) & 1;    // j-half (0: boxes 0-15, 1: boxes 16-31)
    const int ig = t >> 5;          // query pair 0..15
    const int i0 = ig * 2;
    const int jbase = jg * 16;

    // staging mapping: f = t -> (pg, j, c); one float4 per thread per chunk
    const int pg = t & 3;
    const int jj = (t >> 2) & 31;
    const int cs = t >> 7;          // 0..3
    const size_t g0 = ((size_t)(jj * NBATCH + b) * CH + cs) * HW + p0 + pg * 4;
    const int    l0 = (cs * PIX + pg * 4) * LPJ + jj;

    const size_t qoff0 = ((size_t)((i0 + 0) * NBATCH + b) * CH) * HW + p0 + pp;
    const size_t qoff1 = ((size_t)((i0 + 1) * NBATCH + b) * CH) * HW + p0 + pp;

    float s0[16], s1[16];
#pragma unroll
    for (int j = 0; j < 16; ++j) { s0[j] = 0.f; s1[j] = 0.f; }

    float4 r0, rA, rB;
    float qf0[CC], qf1[CC], qn0[CC], qn1[CC];

    // ================= Phase 1: scores = Q.K (1/8 folded into softmax) =================
    r0 = *reinterpret_cast<const float4*>(k + g0);            // K chunk 0
    rA = *reinterpret_cast<const float4*>(k + g0 + CSTRIDE);  // K chunk 1
#pragma unroll
    for (int c = 0; c < CC; ++c) {                            // Q chunk 0
        qf0[c] = q[qoff0 + (size_t)c * HW];
        qf1[c] = q[qoff1 + (size_t)c * HW];
    }
    {
        float* d = &lds[0][l0];
        d[0] = r0.x; d[LPJ] = r0.y; d[2 * LPJ] = r0.z; d[3 * LPJ] = r0.w;
    }
    SYNC();

#pragma unroll 1
    for (int ch = 0; ch < NCHUNK; ++ch) {
        if (ch + 2 < NCHUNK)                                  // K chunk ch+2 (2-deep)
            rB = *reinterpret_cast<const float4*>(k + g0 + (size_t)(ch + 2) * CSTRIDE);
        if (ch + 1 < NCHUNK) {
#pragma unroll
            for (int c = 0; c < CC; ++c) {                    // Q chunk ch+1
                qn0[c] = q[qoff0 + (size_t)((ch + 1) * CC + c) * HW];
                qn1[c] = q[qoff1 + (size_t)((ch + 1) * CC + c) * HW];
            }
        }

        const float* buf = &lds[ch & 1][0];
#pragma unroll
        for (int c = 0; c < CC; ++c) {
            const float* row = &buf[(c * PIX + pp) * LPJ + jbase];
#pragma unroll
            for (int o = 0; o < 4; ++o) {
                float4 kv = *reinterpret_cast<const float4*>(row + o * 4);
                s0[o * 4 + 0] = fmaf(qf0[c], kv.x, s0[o * 4 + 0]);
                s0[o * 4 + 1] = fmaf(qf0[c], kv.y, s0[o * 4 + 1]);
                s0[o * 4 + 2] = fmaf(qf0[c], kv.z, s0[o * 4 + 2]);
                s0[o * 4 + 3] = fmaf(qf0[c], kv.w, s0[o * 4 + 3]);
                s1[o * 4 + 0] = fmaf(qf1[c], kv.x, s1[o * 4 + 0]);
                s1[o * 4 + 1] = fmaf(qf1[c], kv.y, s1[o * 4 + 1]);
                s1[o * 4 + 2] = fmaf(qf1[c], kv.z, s1[o * 4 + 2]);
                s1[o * 4 + 3] = fmaf(qf1[c], kv.w, s1[o * 4 + 3]);
            }
        }

        if (ch + 1 < NCHUNK) {                                // write K chunk ch+1
            float* d = &lds[(ch + 1) & 1][l0];
            d[0] = rA.x; d[LPJ] = rA.y; d[2 * LPJ] = rA.z; d[3 * LPJ] = rA.w;
        }
        SYNC();
        rA = rB;
        if (ch + 1 < NCHUNK) {
#pragma unroll
            for (int c = 0; c < CC; ++c) { qf0[c] = qn0[c]; qf1[c] = qn1[c]; }
        }
    }

    // ============ softmax over j (j-half in regs + one shfl_xor combine) ============
    r0 = *reinterpret_cast<const float4*>(v + g0);            // V chunk 0 (in flight)
    rA = *reinterpret_cast<const float4*>(v + g0 + CSTRIDE);  // V chunk 1
    {
        float m = s0[0];
#pragma unroll
        for (int j = 1; j < 16; ++j) m = fmaxf(m, s0[j]);
        m = fmaxf(m, __shfl_xor(m, 16, 64));                  // combine j-halves
        float sum = 0.f;
#pragma unroll
        for (int j = 0; j < 16; ++j) { float e = __expf((s0[j] - m) * 0.125f); s0[j] = e; sum += e; }
        sum += __shfl_xor(sum, 16, 64);
        float inv = 1.f / sum;
#pragma unroll
        for (int j = 0; j < 16; ++j) s0[j] *= inv;
    }
    {
        float m = s1[0];
#pragma unroll
        for (int j = 1; j < 16; ++j) m = fmaxf(m, s1[j]);
        m = fmaxf(m, __shfl_xor(m, 16, 64));
        float sum = 0.f;
#pragma unroll
        for (int j = 0; j < 16; ++j) { float e = __expf((s1[j] - m) * 0.125f); s1[j] = e; sum += e; }
        sum += __shfl_xor(sum, 16, 64);
        float inv = 1.f / sum;
#pragma unroll
        for (int j = 0; j < 16; ++j) s1[j] *= inv;
    }

    // ================= Phase 2: out = W V (V prefetch 2-deep) =================
    {
        float* d = &lds[0][l0];
        d[0] = r0.x; d[LPJ] = r0.y; d[2 * LPJ] = r0.z; d[3 * LPJ] = r0.w;
    }
    SYNC();

#pragma unroll 1
    for (int ch = 0; ch < NCHUNK; ++ch) {
        if (ch + 2 < NCHUNK)                                  // V chunk ch+2
            rB = *reinterpret_cast<const float4*>(v + g0 + (size_t)(ch + 2) * CSTRIDE);

        float acc0[CC], acc1[CC];
#pragma unroll
        for (int c = 0; c < CC; ++c) { acc0[c] = 0.f; acc1[c] = 0.f; }

        const float* buf = &lds[ch & 1][0];
#pragma unroll
        for (int c = 0; c < CC; ++c) {
            const float* row = &buf[(c * PIX + pp) * LPJ + jbase];
#pragma unroll
            for (int o = 0; o < 4; ++o) {
                float4 vv = *reinterpret_cast<const float4*>(row + o * 4);
                acc0[c] = fmaf(s0[o * 4 + 0], vv.x, acc0[c]);
                acc0[c] = fmaf(s0[o * 4 + 1], vv.y, acc0[c]);
                acc0[c] = fmaf(s0[o * 4 + 2], vv.z, acc0[c]);
                acc0[c] = fmaf(s0[o * 4 + 3], vv.w, acc0[c]);
                acc1[c] = fmaf(s1[o * 4 + 0], vv.x, acc1[c]);
                acc1[c] = fmaf(s1[o * 4 + 1], vv.y, acc1[c]);
                acc1[c] = fmaf(s1[o * 4 + 2], vv.z, acc1[c]);
                acc1[c] = fmaf(s1[o * 4 + 3], vv.w, acc1[c]);
            }
        }
        // combine j-half partials; each partner writes 2 of the 4 channels
#pragma unroll
        for (int c = 0; c < CC; ++c) {
            acc0[c] += __shfl_xor(acc0[c], 16, 64);
            acc1[c] += __shfl_xor(acc1[c], 16, 64);
        }
#pragma unroll
        for (int cc = 0; cc < 2; ++cc) {
            const int c = jg * 2 + cc;
            out[qoff0 + (size_t)(ch * CC + c) * HW] = acc0[c];
            out[qoff1 + (size_t)(ch * CC + c) * HW] = acc1[c];
        }

        if (ch + 1 < NCHUNK) {                                // write V chunk ch+1
            float* d = &lds[(ch + 1) & 1][l0];
            d[0] = rA.x; d[LPJ] = rA.y; d[2 * LPJ] = rA.z; d[3 * LPJ] = rA.w;
        }
        SYNC();
        rA = rB;
    }
}

extern "C" void kernel_launch(void* const* d_in, const int* in_sizes, int n_in,
                              void* d_out, int out_size, void* d_ws, size_t ws_size,
                              hipStream_t stream) {
    const float* q = (const float*)d_in[0];
    const float* k = (const float*)d_in[1];
    const float* v = (const float*)d_in[2];
    float* o = (float*)d_out;
    dim3 grid(NUNITS);   // 1600 blocks of 512
    box_attn_kernel<<<grid, NT, 0, stream>>>(q, k, v, o);
}